// Round 5
// baseline (272.137 us; speedup 1.0000x reference)
//
#include <hip/hip_runtime.h>
#include <cstdint>
#include <cmath>

#define QP    127.0f
#define MINR  1e-6f

// Problem dims: B*N = 8192 tokens, D = 1024, H = 4096
#define MTOK 8192
#define DDIM 1024
#define HDIM 4096

typedef __attribute__((ext_vector_type(4))) int int32x4;

__global__ void zero_scales_kernel(float* g) {
    if (threadIdx.x < 4) g[threadIdx.x] = 0.0f;
}

// ---- fused 3-tensor absmax: block-range partition, atomicMax per tensor ----
__device__ __forceinline__ float wave_block_max(float m) {
    #pragma unroll
    for (int off = 32; off; off >>= 1) m = fmaxf(m, __shfl_down(m, off));
    __shared__ float sm[4];
    int lane = threadIdx.x & 63, w = threadIdx.x >> 6;
    if (lane == 0) sm[w] = m;
    __syncthreads();
    float bm = 0.0f;
    if (threadIdx.x == 0) bm = fmaxf(fmaxf(sm[0], sm[1]), fmaxf(sm[2], sm[3]));
    return bm;
}

__device__ __forceinline__ void absmax_range(const float4* in4, int n4, int bid, int nb,
                                             float* gout) {
    int tid = bid * blockDim.x + threadIdx.x;
    int stride = nb * blockDim.x;
    float m = 0.0f;
    for (int i = tid; i < n4; i += stride) {
        float4 v = in4[i];
        m = fmaxf(m, fmaxf(fmaxf(fabsf(v.x), fabsf(v.y)), fmaxf(fabsf(v.z), fabsf(v.w))));
    }
    float bm = wave_block_max(m);
    if (threadIdx.x == 0) atomicMax((int*)gout, __float_as_int(bm));
}

// blocks [0,1024) -> x, [1024,1536) -> w1, [1536,2048) -> w2
__global__ void absmax3_kernel(const float* __restrict__ x, const float* __restrict__ w1,
                               const float* __restrict__ w2, float* __restrict__ gmax) {
    int b = blockIdx.x;
    if (b < 1024)      absmax_range((const float4*)x,  MTOK * DDIM / 4, b,        1024, gmax + 0);
    else if (b < 1536) absmax_range((const float4*)w1, HDIM * DDIM / 4, b - 1024,  512, gmax + 1);
    else               absmax_range((const float4*)w2, DDIM * HDIM / 4, b - 1536,  512, gmax + 3);
}

// ---------------------------------------------------------------------------
// Panel-packed int8 quantization.
// Layout: tensor [R][K] -> panels of 16 rows x 64 k-bytes (1 KB each), panel
// index (r>>4)*(K>>6) + (k>>6), byte within panel (r&15)*64 + (k&63).
// A wave's global_load_dwordx4 with lane offset (lane&15)*64 + (lane>>4)*16
// then reads EXACTLY one mfma_i32_16x16x64_i8 fragment, fully coalesced --
// same lane->(row, k-chunk) mapping the round-1 kernel used for its LDS reads.
// Reads here are thread-linear float4s (coalesced); writes scatter at 16B
// granularity into panels (small int8 traffic, L2 write-merge absorbs).
// ---------------------------------------------------------------------------
__device__ __forceinline__ int pack4(float4 v, float s) {
    return (((int)rintf(v.x / s)) & 255) | ((((int)rintf(v.y / s)) & 255) << 8) |
           ((((int)rintf(v.z / s)) & 255) << 16) | ((((int)rintf(v.w / s)) & 255) << 24);
}

template<int K>
__device__ __forceinline__ void quant_pack_range(const float* __restrict__ in,
                                                 int8_t* __restrict__ out, int R,
                                                 int bid, int nb,
                                                 const float* __restrict__ gm) {
    const float s = fmaxf(*gm, MINR) / QP;
    const float4* in4 = (const float4*)in;
    const int total = (R / 16) * (K / 16) * 16;  // 16-byte units = R*K/16
    int tid = bid * blockDim.x + threadIdx.x;
    int stride = nb * blockDim.x;
    for (int i = tid; i < total; i += stride) {
        int ib = i << 4;                  // byte index (k0 % 16 == 0, never crosses row)
        int r = ib / K;                   // K constexpr pow2 -> shift
        int k0 = ib & (K - 1);
        int32x4 q;
        q[0] = pack4(in4[i * 4 + 0], s);
        q[1] = pack4(in4[i * 4 + 1], s);
        q[2] = pack4(in4[i * 4 + 2], s);
        q[3] = pack4(in4[i * 4 + 3], s);
        size_t off = ((size_t)((r >> 4) * (K >> 6) + (k0 >> 6)) << 10)
                   + ((r & 15) << 6) + (k0 & 63);
        *(int32x4*)(out + off) = q;
    }
}

// blocks [0,2048) -> x, [2048,3072) -> w1, [3072,4096) -> w2
__global__ void quant3_kernel(const float* __restrict__ x, const float* __restrict__ w1,
                              const float* __restrict__ w2, int8_t* __restrict__ xq,
                              int8_t* __restrict__ w1q, int8_t* __restrict__ w2q,
                              const float* __restrict__ gmax) {
    int b = blockIdx.x;
    if (b < 2048)      quant_pack_range<DDIM>(x,  xq,  MTOK, b,        2048, gmax + 0);
    else if (b < 3072) quant_pack_range<DDIM>(w1, w1q, HDIM, b - 2048, 1024, gmax + 1);
    else               quant_pack_range<HDIM>(w2, w2q, DDIM, b - 3072, 1024, gmax + 3);
}

__global__ void quant_h_kernel(const float* __restrict__ h, int8_t* __restrict__ hq,
                               const float* __restrict__ gm) {
    quant_pack_range<HDIM>(h, hq, MTOK, blockIdx.x, gridDim.x, gm);
}

// ---------------------------------------------------------------------------
// LDS-free direct-operand i8 GEMM.  C = A[M x KD] @ B[ND x KD]^T, panel-packed
// int8 inputs, fp32 epilogue.  128x128 tile, 4 waves (2M x 2N), 64x64/wave.
// Per 64-k step: 8 coalesced global_load_dwordx4 (each IS one MFMA fragment)
// + 16 mfma_i32_16x16x64_i8.  No LDS, no barriers, no waitcnt drains -- the
// compiler pipelines loads across iterations; 3 waves/SIMD (reg-limited only)
// hide L1/L2 latency.  Intra-block 2x fragment duplication absorbed by L1.
// XCD swizzle (bc-fastest logical, the round-2 orientation that measured
// 37.6 MB FETCH): per XCD, br spans 8 panels -> A read once chip-wide; B is
// 4 MB = L2-resident per XCD.
// ---------------------------------------------------------------------------
template<int KD, int ND, bool GELU_EPI>
__global__ __launch_bounds__(256, 3)
void gemm_i8_direct(const int8_t* __restrict__ A, const int8_t* __restrict__ B,
                    const float* __restrict__ bias,
                    const float* __restrict__ gmA, const float* __restrict__ gmB,
                    float* __restrict__ out, float* __restrict__ omax) {
    constexpr int KP = KD >> 6;          // k-panels
    constexpr int NBC = ND / 128;
    const int t = threadIdx.x;
    const int lane = t & 63;
    const int w = t >> 6;
    const int wm = (w >> 1) * 64;
    const int wn = (w & 1) * 64;
    const int lr = lane & 15;
    const int lg = lane >> 4;

    // T1 bijective XCD swizzle, bc-fastest in logical order
    const int chunk = gridDim.x >> 3;
    const int logical = (blockIdx.x & 7) * chunk + (blockIdx.x >> 3);
    const int bc = logical % NBC;
    const int br = logical / NBC;

    const int lo = lr * 64 + lg * 16;    // lane's byte inside a 1 KB panel
    const int8_t* Ap = A + ((size_t)((br * 8 + (wm >> 4)) * KP) << 10) + lo;
    const int8_t* Bp = B + ((size_t)((bc * 8 + (wn >> 4)) * KP) << 10) + lo;

    int32x4 acc[4][4] = {};

    #pragma unroll 2
    for (int kp = 0; kp < KP; ++kp) {
        int32x4 af[4], bf[4];
        #pragma unroll
        for (int m = 0; m < 4; ++m)
            af[m] = *(const int32x4*)(Ap + ((size_t)(m * KP + kp) << 10));
        #pragma unroll
        for (int n = 0; n < 4; ++n)
            bf[n] = *(const int32x4*)(Bp + ((size_t)(n * KP + kp) << 10));
        #pragma unroll
        for (int m = 0; m < 4; ++m)
            #pragma unroll
            for (int n = 0; n < 4; ++n)
                acc[m][n] = __builtin_amdgcn_mfma_i32_16x16x64_i8(af[m], bf[n], acc[m][n], 0, 0, 0);
    }

    // epilogue — replicate reference fp32 op order exactly
    const float sA = fmaxf(*gmA, MINR) / QP;
    const float sB = fmaxf(*gmB, MINR) / QP;
    const float s = sB * sA;
    float lmax = 0.0f;
    #pragma unroll
    for (int m = 0; m < 4; ++m) {
        #pragma unroll
        for (int n = 0; n < 4; ++n) {
            #pragma unroll
            for (int r = 0; r < 4; ++r) {
                int row = br * 128 + wm + m * 16 + lg * 4 + r;
                int col = bc * 128 + wn + n * 16 + lr;
                float f = (float)acc[m][n][r] + bias[col];
                f *= s;
                if (GELU_EPI) {
                    float gg = f * (erff(f / 1.41421356237309504880f) + 1.0f) * 0.5f;
                    out[(size_t)row * ND + col] = gg;
                    lmax = fmaxf(lmax, fabsf(gg));
                } else {
                    out[(size_t)row * ND + col] = f;
                }
            }
        }
    }
    if (GELU_EPI) {
        #pragma unroll
        for (int off = 32; off; off >>= 1) lmax = fmaxf(lmax, __shfl_down(lmax, off));
        __shared__ float red[4];
        if (lane == 0) red[w] = lmax;
        __syncthreads();
        if (t == 0) {
            float bm = fmaxf(fmaxf(red[0], red[1]), fmaxf(red[2], red[3]));
            atomicMax((int*)omax, __float_as_int(bm));
        }
    }
}

extern "C" void kernel_launch(void* const* d_in, const int* in_sizes, int n_in,
                              void* d_out, int out_size, void* d_ws, size_t ws_size,
                              hipStream_t stream) {
    const float* x  = (const float*)d_in[0];   // [8192, 1024]
    const float* w1 = (const float*)d_in[1];   // [4096, 1024]
    const float* b1 = (const float*)d_in[2];   // [4096]
    const float* w2 = (const float*)d_in[3];   // [1024, 4096]
    const float* b2 = (const float*)d_in[4];   // [1024]
    float* out = (float*)d_out;                // [8192, 1024]

    uint8_t* ws = (uint8_t*)d_ws;
    float*  gmax = (float*)ws;                           // [0]=x [1]=w1 [2]=h [3]=w2
    int8_t* xq   = (int8_t*)(ws + 256);                  // 8 MiB, panel-packed
    int8_t* w1q  = xq  + (size_t)MTOK * DDIM;            // 4 MiB
    int8_t* w2q  = w1q + (size_t)HDIM * DDIM;            // 4 MiB
    int8_t* hq   = w2q + (size_t)DDIM * HDIM;            // 32 MiB
    float*  h    = (float*)(hq + (size_t)MTOK * HDIM);   // 128 MiB fp32, linear

    zero_scales_kernel<<<1, 64, 0, stream>>>(gmax);

    absmax3_kernel<<<2048, 256, 0, stream>>>(x, w1, w2, gmax);
    quant3_kernel<<<4096, 256, 0, stream>>>(x, w1, w2, xq, w1q, w2q, gmax);

    // h = gelu((xq @ w1q^T + b1) * s1), fused absmax(h) -> gmax[2]
    // grid = 32*64 = 2048 (%8==0)
    gemm_i8_direct<DDIM, HDIM, true>
        <<<2048, 256, 0, stream>>>(xq, w1q, b1, gmax + 0, gmax + 1, h, gmax + 2);

    quant_h_kernel<<<4096, 256, 0, stream>>>(h, hq, gmax + 2);

    // out = (hq @ w2q^T + b2) * s2 ; grid = 8*64 = 512 (%8==0)
    gemm_i8_direct<HDIM, DDIM, false>
        <<<512, 256, 0, stream>>>(hq, w2q, b2, gmax + 2, gmax + 3, out, nullptr);
}

// Round 6
// 212.217 us; speedup vs baseline: 1.2823x; 1.2823x over previous
//
#include <hip/hip_runtime.h>
#include <cstdint>
#include <cmath>

#define QP    127.0f
#define MINR  1e-6f

// Problem dims: B*N = 8192 tokens, D = 1024, H = 4096
#define MTOK 8192
#define DDIM 1024
#define HDIM 4096

typedef __attribute__((ext_vector_type(4))) int int32x4;

__device__ __forceinline__ void gload16(const void* g, void* l) {
    __builtin_amdgcn_global_load_lds(
        (const __attribute__((address_space(1))) void*)g,
        (__attribute__((address_space(3))) void*)l, 16, 0, 0);
}

// raw barrier + compiler-only memory fence (keeps C-level memory ops and
// gload_lds issues from crossing the barrier; no waitcnt drain implied)
__device__ __forceinline__ void barrier_fence() {
    __builtin_amdgcn_s_barrier();
    asm volatile("" ::: "memory");
}

__global__ void zero_scales_kernel(float* g) {
    if (threadIdx.x < 4) g[threadIdx.x] = 0.0f;
}

// ---- fused 3-tensor absmax: block-range partition, atomicMax per tensor ----
__device__ __forceinline__ float wave_block_max(float m) {
    #pragma unroll
    for (int off = 32; off; off >>= 1) m = fmaxf(m, __shfl_down(m, off));
    __shared__ float sm[4];
    int lane = threadIdx.x & 63, w = threadIdx.x >> 6;
    if (lane == 0) sm[w] = m;
    __syncthreads();
    float bm = 0.0f;
    if (threadIdx.x == 0) bm = fmaxf(fmaxf(sm[0], sm[1]), fmaxf(sm[2], sm[3]));
    return bm;
}

__device__ __forceinline__ void absmax_range(const float4* in4, int n4, int bid, int nb,
                                             float* gout) {
    int tid = bid * blockDim.x + threadIdx.x;
    int stride = nb * blockDim.x;
    float m = 0.0f;
    for (int i = tid; i < n4; i += stride) {
        float4 v = in4[i];
        m = fmaxf(m, fmaxf(fmaxf(fabsf(v.x), fabsf(v.y)), fmaxf(fabsf(v.z), fabsf(v.w))));
    }
    float bm = wave_block_max(m);
    if (threadIdx.x == 0) atomicMax((int*)gout, __float_as_int(bm));
}

// blocks [0,1024) -> x, [1024,1536) -> w1, [1536,2048) -> w2
__global__ void absmax3_kernel(const float* __restrict__ x, const float* __restrict__ w1,
                               const float* __restrict__ w2, float* __restrict__ gmax) {
    int b = blockIdx.x;
    if (b < 1024)      absmax_range((const float4*)x,  MTOK * DDIM / 4, b,        1024, gmax + 0);
    else if (b < 1536) absmax_range((const float4*)w1, HDIM * DDIM / 4, b - 1024,  512, gmax + 1);
    else               absmax_range((const float4*)w2, DDIM * HDIM / 4, b - 1536,  512, gmax + 3);
}

__device__ __forceinline__ void quant_range(const float4* in4, int* out4, int n4,
                                            int bid, int nb, const float* gm) {
    const float s = fmaxf(*gm, MINR) / QP;
    int tid = bid * blockDim.x + threadIdx.x;
    int stride = nb * blockDim.x;
    for (int i = tid; i < n4; i += stride) {
        float4 v = in4[i];
        int q0 = ((int)rintf(v.x / s)) & 255;
        int q1 = ((int)rintf(v.y / s)) & 255;
        int q2 = ((int)rintf(v.z / s)) & 255;
        int q3 = ((int)rintf(v.w / s)) & 255;
        out4[i] = q0 | (q1 << 8) | (q2 << 16) | (q3 << 24);
    }
}

// blocks [0,2048) -> x, [2048,3072) -> w1, [3072,4096) -> w2
__global__ void quant3_kernel(const float* __restrict__ x, const float* __restrict__ w1,
                              const float* __restrict__ w2, int8_t* __restrict__ xq,
                              int8_t* __restrict__ w1q, int8_t* __restrict__ w2q,
                              const float* __restrict__ gmax) {
    int b = blockIdx.x;
    if (b < 2048)      quant_range((const float4*)x,  (int*)xq,  MTOK * DDIM / 4, b,        2048, gmax + 0);
    else if (b < 3072) quant_range((const float4*)w1, (int*)w1q, HDIM * DDIM / 4, b - 2048, 1024, gmax + 1);
    else               quant_range((const float4*)w2, (int*)w2q, DDIM * HDIM / 4, b - 3072, 1024, gmax + 3);
}

__global__ void quant_kernel(const float* __restrict__ in, int8_t* __restrict__ out,
                             int n4, const float* __restrict__ gm) {
    quant_range((const float4*)in, (int*)out, n4, blockIdx.x, gridDim.x, gm);
}

// ---------------------------------------------------------------------------
// Round-1 GEMM structure (128x128 tile, BK=128B, 4 waves, mfma_i32_16x16x64_i8,
// linear-dest global_load_lds + source pre-swizzle, XOR-swizzled ds_read_b128)
// upgraded to the T3 "minimum 2-phase" pipeline:
//   - 2x LDS buffers (64 KB total); stage(kt+1 -> buf^1) issued BEFORE the
//     ds_read+MFMA of buf (stage in flight under ~900 cyc of compute);
//   - raw s_barrier + hand-placed single vmcnt(0) per step, replacing
//     __syncthreads()'s forced vmcnt(0)+lgkmcnt(0) full drain (the m97 stall:
//     measured here as MfmaUtil 15.7% with in-phase co-resident blocks).
// Natural 2D grid (bc fastest): XCD k naturally sees bc%8==k -> B L2-pinned;
// concurrent blocks share A panels (R1 measured FETCH 39 MB; swizzles hurt).
// ---------------------------------------------------------------------------
template<int KD, int ND, bool GELU_EPI>
__global__ __launch_bounds__(256, 2)
void gemm_i8_kernel(const int8_t* __restrict__ A, const int8_t* __restrict__ B,
                    const float* __restrict__ bias,
                    const float* __restrict__ gmA, const float* __restrict__ gmB,
                    float* __restrict__ out, float* __restrict__ omax) {
    constexpr int KT = KD / 128;
    __shared__ int8_t lA[2 * 128 * 128];   // 32 KB
    __shared__ int8_t lB[2 * 128 * 128];   // 32 KB
    const int t = threadIdx.x;
    const int lane = t & 63;
    const int w = t >> 6;
    const int wm = (w >> 1) * 64;
    const int wn = (w & 1) * 64;
    const int lr = lane & 15;
    const int lg = lane >> 4;
    const int br = blockIdx.y, bc = blockIdx.x;

    const int8_t* Ab = A + (size_t)br * 128 * KD;
    const int8_t* Bb = B + (size_t)bc * 128 * KD;

    int32x4 acc[4][4] = {};

    auto stage = [&](int s, int kt) {
        #pragma unroll
        for (int i = 0; i < 4; ++i) {
            int c = t + i * 256;          // 0..1023
            int r = c >> 3;               // tile row 0..127
            int sl = c & 7;               // 16B slot
            int sc = ((sl ^ (r & 7)) << 4);
            gload16(Ab + (size_t)r * KD + kt * 128 + sc, &lA[s * 16384 + c * 16]);
            gload16(Bb + (size_t)r * KD + kt * 128 + sc, &lB[s * 16384 + c * 16]);
        }
    };
    auto compute = [&](int s) {
        #pragma unroll
        for (int kk = 0; kk < 2; ++kk) {
            int32x4 af[4], bf[4];
            #pragma unroll
            for (int m = 0; m < 4; ++m) {
                int r = wm + m * 16 + lr;
                int g = kk * 4 + lg;
                af[m] = *(const int32x4*)&lA[s * 16384 + r * 128 + ((g ^ (r & 7)) << 4)];
            }
            #pragma unroll
            for (int n = 0; n < 4; ++n) {
                int r = wn + n * 16 + lr;
                int g = kk * 4 + lg;
                bf[n] = *(const int32x4*)&lB[s * 16384 + r * 128 + ((g ^ (r & 7)) << 4)];
            }
            #pragma unroll
            for (int m = 0; m < 4; ++m)
                #pragma unroll
                for (int n = 0; n < 4; ++n)
                    acc[m][n] = __builtin_amdgcn_mfma_i32_16x16x64_i8(af[m], bf[n], acc[m][n], 0, 0, 0);
        }
    };

    // prologue: fill buf0, full drain once
    stage(0, 0);
    asm volatile("s_waitcnt vmcnt(0)" ::: "memory");
    barrier_fence();

    int cur = 0;
    for (int kt = 0; kt < KT; ++kt) {
        if (kt + 1 < KT) stage(cur ^ 1, kt + 1);   // next tile in flight...
        compute(cur);                               // ...under this tile's MFMA
        if (kt + 1 < KT) asm volatile("s_waitcnt vmcnt(0)" ::: "memory");
        barrier_fence();                            // one barrier per step
        cur ^= 1;
    }

    // epilogue — replicate reference fp32 op order exactly
    const float sA = fmaxf(*gmA, MINR) / QP;
    const float sB = fmaxf(*gmB, MINR) / QP;
    const float s = sB * sA;
    float lmax = 0.0f;
    #pragma unroll
    for (int m = 0; m < 4; ++m) {
        #pragma unroll
        for (int n = 0; n < 4; ++n) {
            #pragma unroll
            for (int r = 0; r < 4; ++r) {
                int row = br * 128 + wm + m * 16 + lg * 4 + r;
                int col = bc * 128 + wn + n * 16 + lr;
                float f = (float)acc[m][n][r] + bias[col];
                f *= s;
                if (GELU_EPI) {
                    float gg = f * (erff(f / 1.41421356237309504880f) + 1.0f) * 0.5f;
                    out[(size_t)row * ND + col] = gg;
                    lmax = fmaxf(lmax, fabsf(gg));
                } else {
                    out[(size_t)row * ND + col] = f;
                }
            }
        }
    }
    if (GELU_EPI) {
        #pragma unroll
        for (int off = 32; off; off >>= 1) lmax = fmaxf(lmax, __shfl_down(lmax, off));
        float* red = (float*)lA;   // LDS reuse (main loop done, barrier below)
        __syncthreads();
        if (lane == 0) red[w] = lmax;
        __syncthreads();
        if (t == 0) {
            float bm = fmaxf(fmaxf(red[0], red[1]), fmaxf(red[2], red[3]));
            atomicMax((int*)omax, __float_as_int(bm));
        }
    }
}

extern "C" void kernel_launch(void* const* d_in, const int* in_sizes, int n_in,
                              void* d_out, int out_size, void* d_ws, size_t ws_size,
                              hipStream_t stream) {
    const float* x  = (const float*)d_in[0];   // [8192, 1024]
    const float* w1 = (const float*)d_in[1];   // [4096, 1024]
    const float* b1 = (const float*)d_in[2];   // [4096]
    const float* w2 = (const float*)d_in[3];   // [1024, 4096]
    const float* b2 = (const float*)d_in[4];   // [1024]
    float* out = (float*)d_out;                // [8192, 1024]

    uint8_t* ws = (uint8_t*)d_ws;
    float*  gmax = (float*)ws;                           // [0]=x [1]=w1 [2]=h [3]=w2
    int8_t* xq   = (int8_t*)(ws + 256);
    int8_t* w1q  = xq  + (size_t)MTOK * DDIM;
    int8_t* w2q  = w1q + (size_t)HDIM * DDIM;
    int8_t* hq   = w2q + (size_t)DDIM * HDIM;
    float*  h    = (float*)(hq + (size_t)MTOK * HDIM);   // 128 MiB fp32

    zero_scales_kernel<<<1, 64, 0, stream>>>(gmax);

    absmax3_kernel<<<2048, 256, 0, stream>>>(x, w1, w2, gmax);
    quant3_kernel<<<4096, 256, 0, stream>>>(x, w1, w2, xq, w1q, w2q, gmax);

    // h = gelu((xq @ w1q^T + b1) * s1), fused absmax(h) -> gmax[2]
    gemm_i8_kernel<DDIM, HDIM, true>
        <<<dim3(32, 64), 256, 0, stream>>>(xq, w1q, b1, gmax + 0, gmax + 1, h, gmax + 2);

    quant_kernel<<<4096, 256, 0, stream>>>(h, hq, MTOK * HDIM / 4, gmax + 2);

    // out = (hq @ w2q^T + b2) * s2
    gemm_i8_kernel<HDIM, DDIM, false>
        <<<dim3(8, 64), 256, 0, stream>>>(hq, w2q, b2, gmax + 2, gmax + 3, out, nullptr);
}

// Round 7
// 192.994 us; speedup vs baseline: 1.4101x; 1.0996x over previous
//
#include <hip/hip_runtime.h>
#include <hip/hip_fp16.h>
#include <cstdint>
#include <cmath>

#define QP    127.0f
#define MINR  1e-6f

// Problem dims: B*N = 8192 tokens, D = 1024, H = 4096
#define MTOK 8192
#define DDIM 1024
#define HDIM 4096

typedef __attribute__((ext_vector_type(4))) int int32x4;
typedef __attribute__((ext_vector_type(8))) short short8;

__device__ __forceinline__ void gload16(const void* g, void* l) {
    __builtin_amdgcn_global_load_lds(
        (const __attribute__((address_space(1))) void*)g,
        (__attribute__((address_space(3))) void*)l, 16, 0, 0);
}

__global__ void zero_scales_kernel(float* g) {
    if (threadIdx.x < 4) g[threadIdx.x] = 0.0f;
}

// ---- fused 3-tensor absmax: block-range partition, atomicMax per tensor ----
__device__ __forceinline__ float wave_block_max(float m) {
    #pragma unroll
    for (int off = 32; off; off >>= 1) m = fmaxf(m, __shfl_down(m, off));
    __shared__ float sm[4];
    int lane = threadIdx.x & 63, w = threadIdx.x >> 6;
    if (lane == 0) sm[w] = m;
    __syncthreads();
    float bm = 0.0f;
    if (threadIdx.x == 0) bm = fmaxf(fmaxf(sm[0], sm[1]), fmaxf(sm[2], sm[3]));
    return bm;
}

__device__ __forceinline__ void absmax_range(const float4* in4, int n4, int bid, int nb,
                                             float* gout) {
    int tid = bid * blockDim.x + threadIdx.x;
    int stride = nb * blockDim.x;
    float m = 0.0f;
    for (int i = tid; i < n4; i += stride) {
        float4 v = in4[i];
        m = fmaxf(m, fmaxf(fmaxf(fabsf(v.x), fabsf(v.y)), fmaxf(fabsf(v.z), fabsf(v.w))));
    }
    float bm = wave_block_max(m);
    if (threadIdx.x == 0) atomicMax((int*)gout, __float_as_int(bm));
}

// blocks [0,1024) -> x, [1024,1536) -> w1, [1536,2048) -> w2
__global__ void absmax3_kernel(const float* __restrict__ x, const float* __restrict__ w1,
                               const float* __restrict__ w2, float* __restrict__ gmax) {
    int b = blockIdx.x;
    if (b < 1024)      absmax_range((const float4*)x,  MTOK * DDIM / 4, b,        1024, gmax + 0);
    else if (b < 1536) absmax_range((const float4*)w1, HDIM * DDIM / 4, b - 1024,  512, gmax + 1);
    else               absmax_range((const float4*)w2, DDIM * HDIM / 4, b - 1536,  512, gmax + 3);
}

__device__ __forceinline__ void quant_range(const float4* in4, int* out4, int n4,
                                            int bid, int nb, const float* gm) {
    const float s = fmaxf(*gm, MINR) / QP;
    int tid = bid * blockDim.x + threadIdx.x;
    int stride = nb * blockDim.x;
    for (int i = tid; i < n4; i += stride) {
        float4 v = in4[i];
        int q0 = ((int)rintf(v.x / s)) & 255;
        int q1 = ((int)rintf(v.y / s)) & 255;
        int q2 = ((int)rintf(v.z / s)) & 255;
        int q3 = ((int)rintf(v.w / s)) & 255;
        out4[i] = q0 | (q1 << 8) | (q2 << 16) | (q3 << 24);
    }
}

// blocks [0,2048) -> x, [2048,3072) -> w1, [3072,4096) -> w2
__global__ void quant3_kernel(const float* __restrict__ x, const float* __restrict__ w1,
                              const float* __restrict__ w2, int8_t* __restrict__ xq,
                              int8_t* __restrict__ w1q, int8_t* __restrict__ w2q,
                              const float* __restrict__ gmax) {
    int b = blockIdx.x;
    if (b < 2048)      quant_range((const float4*)x,  (int*)xq,  MTOK * DDIM / 4, b,        2048, gmax + 0);
    else if (b < 3072) quant_range((const float4*)w1, (int*)w1q, HDIM * DDIM / 4, b - 2048, 1024, gmax + 1);
    else               quant_range((const float4*)w2, (int*)w2q, DDIM * HDIM / 4, b - 3072, 1024, gmax + 3);
}

// quantize h (fp16) -> int8.  8 halves per thread-iter (16B loads, 8B stores).
__global__ void quant_h_kernel(const __half* __restrict__ h, int8_t* __restrict__ hq,
                               const float* __restrict__ gm) {
    const float s = fmaxf(*gm, MINR) / QP;
    const short8* in8 = (const short8*)h;
    int2* out8 = (int2*)hq;
    const int n8 = MTOK * HDIM / 8;
    int tid = blockIdx.x * blockDim.x + threadIdx.x;
    int stride = gridDim.x * blockDim.x;
    for (int i = tid; i < n8; i += stride) {
        short8 v = in8[i];
        int q[8];
        #pragma unroll
        for (int j = 0; j < 8; ++j) {
            __half_raw r; r.x = (unsigned short)v[j];
            float f = __half2float(__half(r));
            q[j] = ((int)rintf(f / s)) & 255;
        }
        int2 o;
        o.x = q[0] | (q[1] << 8) | (q[2] << 16) | (q[3] << 24);
        o.y = q[4] | (q[5] << 8) | (q[6] << 16) | (q[7] << 24);
        out8[i] = o;
    }
}

// ---------------------------------------------------------------------------
// Round-1 proven GEMM (128x128 tile, BK=128B, 4 waves, mfma_i32_16x16x64_i8,
// linear-dest global_load_lds + source pre-swizzle, XOR-swizzled ds_read_b128,
// plain __syncthreads).  After R2-R6 ablations this loop is the measured
// floor (89 us); schedule variants all regressed.  Round-7 deltas:
//   - OUTT template: GEMM1 stores h as fp16 (halves write traffic; absmax for
//     the scale still computed from exact fp32 pre-cast values);
//   - R2/R5's XCD transform (bc-fastest logical decode), the only swizzle
//     that measured FETCH-positive (37.2-37.6 vs 39.2 MB).
// ---------------------------------------------------------------------------
template<int KD, int ND, bool GELU_EPI, typename OUTT>
__global__ __launch_bounds__(256, 2)
void gemm_i8_kernel(const int8_t* __restrict__ A, const int8_t* __restrict__ B,
                    const float* __restrict__ bias,
                    const float* __restrict__ gmA, const float* __restrict__ gmB,
                    OUTT* __restrict__ out, float* __restrict__ omax) {
    constexpr int NBC = ND / 128;
    __shared__ int8_t lA[128 * 128];
    __shared__ int8_t lB[128 * 128];
    const int t = threadIdx.x;
    const int lane = t & 63;
    const int w = t >> 6;
    const int wm = (w >> 1) * 64;
    const int wn = (w & 1) * 64;
    const int lr = lane & 15;
    const int lg = lane >> 4;

    // XCD transform: gridDim.x % 8 == 0 -> bijective; bc fastest in logical
    // order so each XCD's resident set shares A panels and pins B slices.
    const int chunk = gridDim.x >> 3;
    const int logical = (blockIdx.x & 7) * chunk + (blockIdx.x >> 3);
    const int bc = logical % NBC;
    const int br = logical / NBC;

    const int8_t* Ab = A + (size_t)br * 128 * KD;
    const int8_t* Bb = B + (size_t)bc * 128 * KD;

    int32x4 acc[4][4] = {};

    for (int kt = 0; kt < KD / 128; ++kt) {
        #pragma unroll
        for (int i = 0; i < 4; ++i) {
            int c = t + i * 256;          // 0..1023
            int r = c >> 3;               // tile row 0..127
            int sl = c & 7;               // 16B slot
            int sc = ((sl ^ (r & 7)) << 4);
            gload16(Ab + (size_t)r * KD + kt * 128 + sc, &lA[c * 16]);
            gload16(Bb + (size_t)r * KD + kt * 128 + sc, &lB[c * 16]);
        }
        __syncthreads();

        #pragma unroll
        for (int kk = 0; kk < 2; ++kk) {
            int32x4 af[4], bf[4];
            #pragma unroll
            for (int m = 0; m < 4; ++m) {
                int r = wm + m * 16 + lr;
                int g = kk * 4 + lg;
                af[m] = *(const int32x4*)&lA[r * 128 + ((g ^ (r & 7)) << 4)];
            }
            #pragma unroll
            for (int n = 0; n < 4; ++n) {
                int r = wn + n * 16 + lr;
                int g = kk * 4 + lg;
                bf[n] = *(const int32x4*)&lB[r * 128 + ((g ^ (r & 7)) << 4)];
            }
            #pragma unroll
            for (int m = 0; m < 4; ++m)
                #pragma unroll
                for (int n = 0; n < 4; ++n)
                    acc[m][n] = __builtin_amdgcn_mfma_i32_16x16x64_i8(af[m], bf[n], acc[m][n], 0, 0, 0);
        }
        __syncthreads();
    }

    // epilogue — replicate reference fp32 op order exactly; absmax from the
    // full-precision fp32 value (scale semantics preserved even for fp16 out)
    const float sA = fmaxf(*gmA, MINR) / QP;
    const float sB = fmaxf(*gmB, MINR) / QP;
    const float s = sB * sA;
    float lmax = 0.0f;
    #pragma unroll
    for (int m = 0; m < 4; ++m) {
        #pragma unroll
        for (int n = 0; n < 4; ++n) {
            #pragma unroll
            for (int r = 0; r < 4; ++r) {
                int row = br * 128 + wm + m * 16 + lg * 4 + r;
                int col = bc * 128 + wn + n * 16 + lr;
                float f = (float)acc[m][n][r] + bias[col];
                f *= s;
                if (GELU_EPI) {
                    float gg = f * (erff(f / 1.41421356237309504880f) + 1.0f) * 0.5f;
                    out[(size_t)row * ND + col] = (OUTT)gg;
                    lmax = fmaxf(lmax, fabsf(gg));
                } else {
                    out[(size_t)row * ND + col] = (OUTT)f;
                }
            }
        }
    }
    if (GELU_EPI) {
        #pragma unroll
        for (int off = 32; off; off >>= 1) lmax = fmaxf(lmax, __shfl_down(lmax, off));
        __shared__ float red[4];
        if (lane == 0) red[w] = lmax;
        __syncthreads();
        if (t == 0) {
            float bm = fmaxf(fmaxf(red[0], red[1]), fmaxf(red[2], red[3]));
            atomicMax((int*)omax, __float_as_int(bm));
        }
    }
}

extern "C" void kernel_launch(void* const* d_in, const int* in_sizes, int n_in,
                              void* d_out, int out_size, void* d_ws, size_t ws_size,
                              hipStream_t stream) {
    const float* x  = (const float*)d_in[0];   // [8192, 1024]
    const float* w1 = (const float*)d_in[1];   // [4096, 1024]
    const float* b1 = (const float*)d_in[2];   // [4096]
    const float* w2 = (const float*)d_in[3];   // [1024, 4096]
    const float* b2 = (const float*)d_in[4];   // [1024]
    float* out = (float*)d_out;                // [8192, 1024]

    uint8_t* ws = (uint8_t*)d_ws;
    float*  gmax = (float*)ws;                           // [0]=x [1]=w1 [2]=h [3]=w2
    int8_t* xq   = (int8_t*)(ws + 256);                  // 8 MiB
    int8_t* w1q  = xq  + (size_t)MTOK * DDIM;            // 4 MiB
    int8_t* w2q  = w1q + (size_t)HDIM * DDIM;            // 4 MiB
    int8_t* hq   = w2q + (size_t)DDIM * HDIM;            // 32 MiB
    __half* h    = (__half*)(hq + (size_t)MTOK * HDIM);  // 64 MiB fp16

    zero_scales_kernel<<<1, 64, 0, stream>>>(gmax);

    absmax3_kernel<<<2048, 256, 0, stream>>>(x, w1, w2, gmax);
    quant3_kernel<<<4096, 256, 0, stream>>>(x, w1, w2, xq, w1q, w2q, gmax);

    // h(fp16) = gelu((xq @ w1q^T + b1) * s1), fused fp32 absmax(h) -> gmax[2]
    // grid = 2048 (%8==0)
    gemm_i8_kernel<DDIM, HDIM, true, __half>
        <<<2048, 256, 0, stream>>>(xq, w1q, b1, gmax + 0, gmax + 1, h, gmax + 2);

    quant_h_kernel<<<2048, 256, 0, stream>>>(h, hq, gmax + 2);

    // out = (hq @ w2q^T + b2) * s2 ; grid = 512 (%8==0)
    gemm_i8_kernel<HDIM, DDIM, false, float>
        <<<512, 256, 0, stream>>>(hq, w2q, b2, gmax + 2, gmax + 3, out, nullptr);
}